// Round 4
// baseline (258.358 us; speedup 1.0000x reference)
//
#include <hip/hip_runtime.h>
#include <hip/hip_fp16.h>
#include <math.h>

#define NEG_SLOPE 0.2f
#define BKT_SHIFT 8
#define BKT_NODES (1 << BKT_SHIFT)       // 256 nodes per bucket
#define BKT_CAP 512                      // >= B = ceil(N/256) = 391
#define BKT_FCAP 6144                    // fixed edge capacity per bucket (avg 4092)
#define BKT_SHARD (BKT_FCAP / 4)         // 1536 per shard (expected ~1026, 16-sigma margin)
#define P1_CHUNK 4096

typedef _Float16 f16x8 __attribute__((ext_vector_type(8)));
typedef float    f32x4 __attribute__((ext_vector_type(4)));
union FU  { uint4 u; f16x8 f; };
union H2U { __half2 h; unsigned u; };

__device__ __forceinline__ float lrelu(float x){ return fmaxf(x, NEG_SLOPE * x); }
__device__ __forceinline__ float elu_fast(float x){
  float t = __expf(fminf(x, 0.f)) - 1.f;
  return x > 0.f ? x : t;
}

// ---------------- bucketed CSR build (single-pass, fixed-cap buckets) ----------------
// bucket b = dst >> 8. pairs packed: (dst&255)<<17 | src  (src < 2^17)
// bktCur sharded x4 by blockIdx&3 to cut same-address atomic serialization.
// Block 0 additionally packs the W fragments (saves a dispatch).

__global__ __launch_bounds__(256) void k_p1(const int* __restrict__ src, const int* __restrict__ dst,
                                            int E, int B, int* __restrict__ bktCur,
                                            unsigned* __restrict__ pairs,
                                            const float* __restrict__ W1, const float* __restrict__ W2,
                                            uint4* __restrict__ W1f, uint4* __restrict__ W2f){
  __shared__ int h[BKT_CAP], base[BKT_CAP], cur[BKT_CAP];
  int tid = threadIdx.x;
  if (blockIdx.x == 0){
    // W1 fragments: fs = t*4+s (t,s in 0..3); W2: fs = t*2+s (t 0..3, s 0..1)
    for (int idx = tid; idx < 16 * 64; idx += 256){
      int lane = idx & 63, fs = idx >> 6;
      int t = fs >> 2, s = fs & 3;
      int m = lane & 15, quad = lane >> 4;
      f16x8 v;
      #pragma unroll
      for (int j = 0; j < 8; ++j)
        v[j] = (_Float16)W1[(s * 32 + quad * 8 + j) * 64 + t * 16 + m];
      FU fu; fu.f = v;
      W1f[fs * 64 + lane] = fu.u;
    }
    for (int idx = tid; idx < 8 * 64; idx += 256){
      int lane = idx & 63, fs = idx >> 6;
      int t = fs >> 1, s = fs & 1;
      int m = lane & 15, quad = lane >> 4;
      f16x8 v;
      #pragma unroll
      for (int j = 0; j < 8; ++j)
        v[j] = (_Float16)W2[(s * 32 + quad * 8 + j) * 64 + t * 16 + m];
      FU fu; fu.f = v;
      W2f[fs * 64 + lane] = fu.u;
    }
  }
  for (int i = tid; i < BKT_CAP; i += 256){ h[i] = 0; cur[i] = 0; }
  __syncthreads();
  int beg = blockIdx.x * P1_CHUNK;
  int end = min(beg + P1_CHUNK, E);
  int shard = blockIdx.x & 3;
  int m4 = (end - beg) >> 2;
  const int4* d4 = (const int4*)(dst + beg);
  const int4* s4 = (const int4*)(src + beg);
  for (int i = tid; i < m4; i += 256){
    int4 d = d4[i];
    atomicAdd(&h[d.x >> BKT_SHIFT], 1); atomicAdd(&h[d.y >> BKT_SHIFT], 1);
    atomicAdd(&h[d.z >> BKT_SHIFT], 1); atomicAdd(&h[d.w >> BKT_SHIFT], 1);
  }
  for (int i = beg + (m4 << 2) + tid; i < end; i += 256)
    atomicAdd(&h[dst[i] >> BKT_SHIFT], 1);
  __syncthreads();
  for (int i = tid; i < B; i += 256)
    if (h[i]) base[i] = i * BKT_FCAP + shard * BKT_SHARD + atomicAdd(&bktCur[i * 4 + shard], h[i]);
  __syncthreads();
  for (int i = tid; i < m4; i += 256){
    int4 d = d4[i]; int4 s = s4[i];
    int b0 = d.x >> BKT_SHIFT, b1 = d.y >> BKT_SHIFT, b2 = d.z >> BKT_SHIFT, b3 = d.w >> BKT_SHIFT;
    int p0 = base[b0] + atomicAdd(&cur[b0], 1);
    pairs[p0] = ((unsigned)(d.x & (BKT_NODES-1)) << 17) | (unsigned)s.x;
    int p1 = base[b1] + atomicAdd(&cur[b1], 1);
    pairs[p1] = ((unsigned)(d.y & (BKT_NODES-1)) << 17) | (unsigned)s.y;
    int p2 = base[b2] + atomicAdd(&cur[b2], 1);
    pairs[p2] = ((unsigned)(d.z & (BKT_NODES-1)) << 17) | (unsigned)s.z;
    int p3 = base[b3] + atomicAdd(&cur[b3], 1);
    pairs[p3] = ((unsigned)(d.w & (BKT_NODES-1)) << 17) | (unsigned)s.w;
  }
  for (int i = beg + (m4 << 2) + tid; i < end; i += 256){
    int d = dst[i], s = src[i];
    int b = d >> BKT_SHIFT;
    int p = base[b] + atomicAdd(&cur[b], 1);
    pairs[p] = ((unsigned)(d & (BKT_NODES-1)) << 17) | (unsigned)s;
  }
}

// one block (256 thr) per bucket: LDS hist -> scan -> offs2 (int2{beg,end}) + padded col
// reads the 4 shard sub-ranges of the bucket's FCAP region.
__global__ __launch_bounds__(256) void k_p2(const unsigned* __restrict__ pairs,
                                            const int* __restrict__ bktCur,
                                            int N, int2* __restrict__ offs2, int* __restrict__ col){
  __shared__ int sc[BKT_NODES], cu[BKT_NODES];
  int b = blockIdx.x, tid = threadIdx.x;
  int nbase = b << BKT_SHIFT;
  int bs = b * BKT_FCAP;
  sc[tid] = 0;
  __syncthreads();
  #pragma unroll
  for (int s = 0; s < 4; ++s){
    int ss_ = bs + s * BKT_SHARD;
    int se_ = ss_ + bktCur[b * 4 + s];
    for (int i = ss_ + tid; i < se_; i += 256)
      atomicAdd(&sc[pairs[i] >> 17], 1);
  }
  __syncthreads();
  int v = sc[tid];
  for (int o = 1; o < 256; o <<= 1){
    int x = (tid >= o) ? sc[tid - o] : 0;
    __syncthreads();
    sc[tid] += x;
    __syncthreads();
  }
  int ex = sc[tid] - v;
  cu[tid] = bs + ex;
  if (nbase + tid < N) offs2[nbase + tid] = make_int2(bs + ex, bs + ex + v);
  __syncthreads();
  #pragma unroll
  for (int s = 0; s < 4; ++s){
    int ss_ = bs + s * BKT_SHARD;
    int se_ = ss_ + bktCur[b * 4 + s];
    for (int i = ss_ + tid; i < se_; i += 256){
      unsigned pr = pairs[i];
      int p = atomicAdd(&cu[pr >> 17], 1);
      col[p] = (int)(pr & 0x1FFFFu);
    }
  }
}

// ---------------- MFMA GEMM 1: H(fp16)[n,64] = X(fp32)[n,128] @ W1, + logits ----------------
__global__ __launch_bounds__(256) void k_mgemm1(
    const float* __restrict__ X, const uint4* __restrict__ Wf,
    const float* __restrict__ a_src, const float* __restrict__ a_dst,
    uint2* __restrict__ H, float* __restrict__ as_, float* __restrict__ ad_, int n)
{
  int lane = threadIdx.x & 63, wv = threadIdx.x >> 6;
  int quad = lane >> 4, nn = lane & 15;
  int rowb = blockIdx.x * 64 + wv * 16;
  int row = rowb + nn;
  bool ok = row < n;
  int rowc = ok ? row : n - 1;

  f16x8 af[4][4];
  #pragma unroll
  for (int t = 0; t < 4; ++t)
    #pragma unroll
    for (int s = 0; s < 4; ++s){
      FU fu; fu.u = Wf[(t * 4 + s) * 64 + lane];
      af[t][s] = fu.f;
    }

  const float4* Xr = (const float4*)(X + (size_t)rowc * 128);
  float4 xb[4][2];
  #pragma unroll
  for (int s = 0; s < 4; ++s){
    xb[s][0] = Xr[s * 8 + quad * 2];
    xb[s][1] = Xr[s * 8 + quad * 2 + 1];
  }

  f32x4 acc[4] = {};
  #pragma unroll
  for (int s = 0; s < 4; ++s){
    f16x8 bf;
    bf[0] = (_Float16)xb[s][0].x; bf[1] = (_Float16)xb[s][0].y;
    bf[2] = (_Float16)xb[s][0].z; bf[3] = (_Float16)xb[s][0].w;
    bf[4] = (_Float16)xb[s][1].x; bf[5] = (_Float16)xb[s][1].y;
    bf[6] = (_Float16)xb[s][1].z; bf[7] = (_Float16)xb[s][1].w;
    #pragma unroll
    for (int t = 0; t < 4; ++t)
      acc[t] = __builtin_amdgcn_mfma_f32_16x16x32_f16(af[t][s], bf, acc[t], 0, 0, 0);
  }

  if (ok){
    #pragma unroll
    for (int t = 0; t < 4; ++t){
      H2U p0, p1;
      p0.h = __floats2half2_rn(acc[t][0], acc[t][1]);
      p1.h = __floats2half2_rn(acc[t][2], acc[t][3]);
      H[(size_t)row * 16 + t * 4 + quad] = make_uint2(p0.u, p1.u);
    }
  }
  float sl = 0.f, dl = 0.f;
  #pragma unroll
  for (int t = 0; t < 4; ++t){
    float4 a4 = ((const float4*)a_src)[t * 4 + quad];
    float4 d4 = ((const float4*)a_dst)[t * 4 + quad];
    sl += acc[t][0] * a4.x + acc[t][1] * a4.y + acc[t][2] * a4.z + acc[t][3] * a4.w;
    dl += acc[t][0] * d4.x + acc[t][1] * d4.y + acc[t][2] * d4.z + acc[t][3] * d4.w;
  }
  sl += __shfl_xor(sl, 16, 64); sl += __shfl_xor(sl, 32, 64);
  dl += __shfl_xor(dl, 16, 64); dl += __shfl_xor(dl, 32, 64);
  if (lane < 16 && ok){ as_[row] = sl; ad_[row] = dl; }
}

// ---------------- MFMA GEMM 2: h2(fp16) = h1e(fp16)[n,64] @ W2, + logits ----------------
__global__ __launch_bounds__(256) void k_mgemm2(
    const uint4* __restrict__ Xh, const uint4* __restrict__ Wf,
    const float* __restrict__ a_src, const float* __restrict__ a_dst,
    uint2* __restrict__ H, float* __restrict__ as_, float* __restrict__ ad_, int n)
{
  int lane = threadIdx.x & 63, wv = threadIdx.x >> 6;
  int quad = lane >> 4, nn = lane & 15;
  int rowb = blockIdx.x * 64 + wv * 16;
  int row = rowb + nn;
  bool ok = row < n;
  int rowc = ok ? row : n - 1;

  f16x8 af[4][2];
  #pragma unroll
  for (int t = 0; t < 4; ++t)
    #pragma unroll
    for (int s = 0; s < 2; ++s){
      FU fu; fu.u = Wf[(t * 2 + s) * 64 + lane];
      af[t][s] = fu.f;
    }

  f16x8 bf[2];
  #pragma unroll
  for (int s = 0; s < 2; ++s){
    FU fu; fu.u = Xh[(size_t)rowc * 8 + s * 4 + quad];
    bf[s] = fu.f;
  }

  f32x4 acc[4] = {};
  #pragma unroll
  for (int s = 0; s < 2; ++s)
    #pragma unroll
    for (int t = 0; t < 4; ++t)
      acc[t] = __builtin_amdgcn_mfma_f32_16x16x32_f16(af[t][s], bf[s], acc[t], 0, 0, 0);

  if (ok){
    #pragma unroll
    for (int t = 0; t < 4; ++t){
      H2U p0, p1;
      p0.h = __floats2half2_rn(acc[t][0], acc[t][1]);
      p1.h = __floats2half2_rn(acc[t][2], acc[t][3]);
      H[(size_t)row * 16 + t * 4 + quad] = make_uint2(p0.u, p1.u);
    }
  }
  float sl = 0.f, dl = 0.f;
  #pragma unroll
  for (int t = 0; t < 4; ++t){
    float4 a4 = ((const float4*)a_src)[t * 4 + quad];
    float4 d4 = ((const float4*)a_dst)[t * 4 + quad];
    sl += acc[t][0] * a4.x + acc[t][1] * a4.y + acc[t][2] * a4.z + acc[t][3] * a4.w;
    dl += acc[t][0] * d4.x + acc[t][1] * d4.y + acc[t][2] * d4.z + acc[t][3] * d4.w;
  }
  sl += __shfl_xor(sl, 16, 64); sl += __shfl_xor(sl, 32, 64);
  dl += __shfl_xor(dl, 16, 64); dl += __shfl_xor(dl, 32, 64);
  if (lane < 16 && ok){ as_[row] = sl; ad_[row] = dl; }
}

// ---------------- attention aggregation ----------------
// 8 nodes/wave, x4 unroll (round-0 proven body); each wave processes TWO
// 32-node groups sequentially -> grid = (N+63)/64 = 1563 blocks = 6.1/CU,
// all resident for the whole kernel (sustained ~76% occupancy vs 53% two-round avg).
#define FMA8(e, hv) { const __half2* hp = (const __half2*)&(hv);               \
  a[0]=fmaf(e, __half2float(hp[0].x), a[0]); a[1]=fmaf(e, __half2float(hp[0].y), a[1]); \
  a[2]=fmaf(e, __half2float(hp[1].x), a[2]); a[3]=fmaf(e, __half2float(hp[1].y), a[3]); \
  a[4]=fmaf(e, __half2float(hp[2].x), a[4]); a[5]=fmaf(e, __half2float(hp[2].y), a[5]); \
  a[6]=fmaf(e, __half2float(hp[3].x), a[6]); a[7]=fmaf(e, __half2float(hp[3].y), a[7]); }

__device__ __forceinline__ void agg_core(
    const int2* __restrict__ offs2, const int* __restrict__ col,
    const uint4* __restrict__ H4, const float* __restrict__ as_, const float* __restrict__ ad_,
    int node, int c8, float& denom, float a[8])
{
  int2 be2 = offs2[node];
  int beg = be2.x, d = be2.y - be2.x;
  int maxd = d;
  maxd = max(maxd, __shfl_xor(maxd, 8, 64));
  maxd = max(maxd, __shfl_xor(maxd, 16, 64));
  maxd = max(maxd, __shfl_xor(maxd, 32, 64));
  float adv = ad_[node];
  float exs = __expf(lrelu(as_[node] + adv));
  uint4 hself = H4[(size_t)node * 8 + c8];
  denom = exs;
  { const __half2* hp = (const __half2*)&hself;
    #pragma unroll
    for (int i = 0; i < 4; ++i){
      a[2*i]   = exs * __half2float(hp[i].x);
      a[2*i+1] = exs * __half2float(hp[i].y);
    } }
  for (int j = 0; j < maxd; j += 4){
    int ss[4]; float asv[4]; uint4 hv[4];
    #pragma unroll
    for (int u = 0; u < 4; ++u) ss[u] = (j + u < d) ? col[beg + j + u] : 0;
    #pragma unroll
    for (int u = 0; u < 4; ++u) asv[u] = as_[ss[u]];
    #pragma unroll
    for (int u = 0; u < 4; ++u) hv[u] = H4[(size_t)ss[u] * 8 + c8];
    #pragma unroll
    for (int u = 0; u < 4; ++u){
      float e = (j + u < d) ? __expf(lrelu(asv[u] + adv)) : 0.f;
      denom += e;
      FMA8(e, hv[u])
    }
  }
}

__global__ __launch_bounds__(256) void k_agg1(
    const int2* __restrict__ offs2, const int* __restrict__ col,
    const uint4* __restrict__ H4, const float* __restrict__ as_, const float* __restrict__ ad_,
    const float* __restrict__ bias, uint4* __restrict__ outH, int n)
{
  int lane = threadIdx.x & 63, w = threadIdx.x >> 6;
  int m = lane >> 3, c8 = lane & 7;
  float4 b0 = *(const float4*)&bias[8 * c8];
  float4 b1 = *(const float4*)&bias[8 * c8 + 4];
  float bb[8] = {b0.x, b0.y, b0.z, b0.w, b1.x, b1.y, b1.z, b1.w};
  #pragma unroll
  for (int g = 0; g < 2; ++g){
    int node0 = blockIdx.x * 64 + g * 32 + w * 8 + m;
    bool ok = node0 < n;
    int node = ok ? node0 : n - 1;
    float denom; float a[8];
    agg_core(offs2, col, H4, as_, ad_, node, c8, denom, a);
    float inv = 1.f / denom;
    unsigned oh[4];
    #pragma unroll
    for (int i = 0; i < 4; ++i){
      float v0 = elu_fast(fmaf(a[2*i],   inv, bb[2*i]));
      float v1 = elu_fast(fmaf(a[2*i+1], inv, bb[2*i+1]));
      __half2 h = __floats2half2_rn(v0, v1);
      oh[i] = *(unsigned*)&h;
    }
    if (ok){
      uint4 ov; ov.x = oh[0]; ov.y = oh[1]; ov.z = oh[2]; ov.w = oh[3];
      outH[(size_t)node * 8 + c8] = ov;
    }
  }
}

__global__ __launch_bounds__(256) void k_agg2(
    const int2* __restrict__ offs2, const int* __restrict__ col,
    const uint4* __restrict__ H4, const float* __restrict__ as_, const float* __restrict__ ad_,
    const float* __restrict__ bias, const float* __restrict__ Wout, const float* __restrict__ bout,
    float* __restrict__ out, int n)
{
  int lane = threadIdx.x & 63, w = threadIdx.x >> 6;
  int m = lane >> 3, c8 = lane & 7;
  float4 b0 = *(const float4*)&bias[8 * c8];
  float4 b1 = *(const float4*)&bias[8 * c8 + 4];
  float4 w0 = *(const float4*)&Wout[8 * c8];
  float4 w1 = *(const float4*)&Wout[8 * c8 + 4];
  float bb[8] = {b0.x, b0.y, b0.z, b0.w, b1.x, b1.y, b1.z, b1.w};
  float ww[8] = {w0.x, w0.y, w0.z, w0.w, w1.x, w1.y, w1.z, w1.w};
  #pragma unroll
  for (int g = 0; g < 2; ++g){
    int node0 = blockIdx.x * 64 + g * 32 + w * 8 + m;
    bool ok = node0 < n;
    int node = ok ? node0 : n - 1;
    float denom; float a[8];
    agg_core(offs2, col, H4, as_, ad_, node, c8, denom, a);
    float inv = 1.f / denom;
    float p = 0.f;
    #pragma unroll
    for (int i = 0; i < 8; ++i)
      p += elu_fast(fmaf(a[i], inv, bb[i])) * ww[i];
    p += __shfl_xor(p, 1, 64); p += __shfl_xor(p, 2, 64); p += __shfl_xor(p, 4, 64);
    if (c8 == 0 && ok) out[node] = p + bout[0];
  }
}

// ---------------- launch ----------------
extern "C" void kernel_launch(void* const* d_in, const int* in_sizes, int n_in,
                              void* d_out, int out_size, void* d_ws, size_t ws_size,
                              hipStream_t stream)
{
  const float* x    = (const float*)d_in[0];
  const int*   ei   = (const int*)d_in[1];   // int32 [2, E] flat
  const float* W1   = (const float*)d_in[2];
  const float* as1w = (const float*)d_in[3];
  const float* ad1w = (const float*)d_in[4];
  const float* b1   = (const float*)d_in[5];
  const float* W2   = (const float*)d_in[6];
  const float* as2w = (const float*)d_in[7];
  const float* ad2w = (const float*)d_in[8];
  const float* b2   = (const float*)d_in[9];
  const float* Wout = (const float*)d_in[10];
  const float* bout = (const float*)d_in[11];
  float* out = (float*)d_out;

  const int N = in_sizes[0] / 128;
  const int E = in_sizes[1] / 2;
  const int* srcA = ei;
  const int* dstA = ei + E;
  const int B = (N + BKT_NODES - 1) >> BKT_SHIFT;   // 391 (<= BKT_CAP); src < 2^17 required

  char* p = (char*)d_ws;
  auto alloc = [&](size_t bytes){ char* r = p; p += (bytes + 255) & ~255ull; return r; };
  int*   bktCur = (int*)alloc(BKT_CAP * 4 * 4);              // x4 shards
  int2*  offs2  = (int2*)alloc((size_t)N * 8);
  int*   col    = (int*)alloc((size_t)B * BKT_FCAP * 4);     // padded CSR col (9.6 MB)
  float* vas1 = (float*)alloc((size_t)N * 4);
  float* vad1 = (float*)alloc((size_t)N * 4);
  float* vas2 = (float*)alloc((size_t)N * 4);
  float* vad2 = (float*)alloc((size_t)N * 4);
  uint4* w1f  = (uint4*)alloc(16 * 64 * 16);
  uint4* w2f  = (uint4*)alloc(8 * 64 * 16);
  uint2* h1   = (uint2*)alloc((size_t)N * 64 * 2);   // fp16 [N,64]
  uint2* h1e  = (uint2*)alloc((size_t)N * 64 * 2);   // fp16 [N,64]
  unsigned* pairs = (unsigned*)h1;  // padded pairs (9.6 MB) dead before k_mgemm1 writes h1 (12.8 MB)
  uint2* h2   = h1;                 // h1 dead after k_agg1

  hipMemsetAsync(bktCur, 0, BKT_CAP * 4 * 4, stream);

  int nchunk = (E + P1_CHUNK - 1) / P1_CHUNK;
  k_p1<<<nchunk, 256, 0, stream>>>(srcA, dstA, E, B, bktCur, pairs, W1, W2, w1f, w2f);
  k_p2<<<B, 256, 0, stream>>>(pairs, bktCur, N, offs2, col);

  int gblocks = (N + 63) / 64;
  int ablocks = (N + 63) / 64;   // 64 nodes per block (4 waves x 8 nodes x 2 sequential groups)
  k_mgemm1<<<gblocks, 256, 0, stream>>>(x, w1f, as1w, ad1w, h1, vas1, vad1, N);
  k_agg1  <<<ablocks, 256, 0, stream>>>(offs2, col, (const uint4*)h1, vas1, vad1, b1, (uint4*)h1e, N);
  k_mgemm2<<<gblocks, 256, 0, stream>>>((const uint4*)h1e, w2f, as2w, ad2w, h2, vas2, vad2, N);
  k_agg2  <<<ablocks, 256, 0, stream>>>(offs2, col, (const uint4*)h2, vas2, vad2, b2, Wout, bout, out, N);
}

// Round 5
// 245.295 us; speedup vs baseline: 1.0533x; 1.0533x over previous
//
#include <hip/hip_runtime.h>
#include <hip/hip_fp16.h>
#include <math.h>

#define NEG_SLOPE 0.2f
#define BKT_SHIFT 8
#define BKT_NODES (1 << BKT_SHIFT)       // 256 nodes per bucket
#define BKT_CAP 512                      // >= B = ceil(N/256) = 391
#define BKT_FCAP 6144                    // fixed edge capacity per bucket (avg 4092)
#define BKT_SHARD (BKT_FCAP / 4)         // 1536 per shard (expected ~1026, 16-sigma margin)
#define P1_CHUNK 4096

typedef _Float16 f16x8 __attribute__((ext_vector_type(8)));
typedef float    f32x4 __attribute__((ext_vector_type(4)));
union FU  { uint4 u; f16x8 f; };
union H2U { __half2 h; unsigned u; };

__device__ __forceinline__ float lrelu(float x){ return fmaxf(x, NEG_SLOPE * x); }
__device__ __forceinline__ float elu_fast(float x){
  float t = __expf(fminf(x, 0.f)) - 1.f;
  return x > 0.f ? x : t;
}

// ---------------- bucketed CSR build (single-pass, fixed-cap buckets) ----------------
// bucket b = dst >> 8. pairs packed: (dst&255)<<17 | src  (src < 2^17)
// bktCur sharded x4 by blockIdx&3 to cut same-address atomic serialization.
// Block 0 additionally packs the W fragments (saves a dispatch).

__global__ __launch_bounds__(256) void k_p1(const int* __restrict__ src, const int* __restrict__ dst,
                                            int E, int B, int* __restrict__ bktCur,
                                            unsigned* __restrict__ pairs,
                                            const float* __restrict__ W1, const float* __restrict__ W2,
                                            uint4* __restrict__ W1f, uint4* __restrict__ W2f){
  __shared__ int h[BKT_CAP], base[BKT_CAP], cur[BKT_CAP];
  int tid = threadIdx.x;
  if (blockIdx.x == 0){
    // W1 fragments: fs = t*4+s (t,s in 0..3); W2: fs = t*2+s (t 0..3, s 0..1)
    for (int idx = tid; idx < 16 * 64; idx += 256){
      int lane = idx & 63, fs = idx >> 6;
      int t = fs >> 2, s = fs & 3;
      int m = lane & 15, quad = lane >> 4;
      f16x8 v;
      #pragma unroll
      for (int j = 0; j < 8; ++j)
        v[j] = (_Float16)W1[(s * 32 + quad * 8 + j) * 64 + t * 16 + m];
      FU fu; fu.f = v;
      W1f[fs * 64 + lane] = fu.u;
    }
    for (int idx = tid; idx < 8 * 64; idx += 256){
      int lane = idx & 63, fs = idx >> 6;
      int t = fs >> 1, s = fs & 1;
      int m = lane & 15, quad = lane >> 4;
      f16x8 v;
      #pragma unroll
      for (int j = 0; j < 8; ++j)
        v[j] = (_Float16)W2[(s * 32 + quad * 8 + j) * 64 + t * 16 + m];
      FU fu; fu.f = v;
      W2f[fs * 64 + lane] = fu.u;
    }
  }
  for (int i = tid; i < BKT_CAP; i += 256){ h[i] = 0; cur[i] = 0; }
  __syncthreads();
  int beg = blockIdx.x * P1_CHUNK;
  int end = min(beg + P1_CHUNK, E);
  int shard = blockIdx.x & 3;
  int m4 = (end - beg) >> 2;
  const int4* d4 = (const int4*)(dst + beg);
  const int4* s4 = (const int4*)(src + beg);
  for (int i = tid; i < m4; i += 256){
    int4 d = d4[i];
    atomicAdd(&h[d.x >> BKT_SHIFT], 1); atomicAdd(&h[d.y >> BKT_SHIFT], 1);
    atomicAdd(&h[d.z >> BKT_SHIFT], 1); atomicAdd(&h[d.w >> BKT_SHIFT], 1);
  }
  for (int i = beg + (m4 << 2) + tid; i < end; i += 256)
    atomicAdd(&h[dst[i] >> BKT_SHIFT], 1);
  __syncthreads();
  for (int i = tid; i < B; i += 256)
    if (h[i]) base[i] = i * BKT_FCAP + shard * BKT_SHARD + atomicAdd(&bktCur[i * 4 + shard], h[i]);
  __syncthreads();
  for (int i = tid; i < m4; i += 256){
    int4 d = d4[i]; int4 s = s4[i];
    int b0 = d.x >> BKT_SHIFT, b1 = d.y >> BKT_SHIFT, b2 = d.z >> BKT_SHIFT, b3 = d.w >> BKT_SHIFT;
    int p0 = base[b0] + atomicAdd(&cur[b0], 1);
    pairs[p0] = ((unsigned)(d.x & (BKT_NODES-1)) << 17) | (unsigned)s.x;
    int p1 = base[b1] + atomicAdd(&cur[b1], 1);
    pairs[p1] = ((unsigned)(d.y & (BKT_NODES-1)) << 17) | (unsigned)s.y;
    int p2 = base[b2] + atomicAdd(&cur[b2], 1);
    pairs[p2] = ((unsigned)(d.z & (BKT_NODES-1)) << 17) | (unsigned)s.z;
    int p3 = base[b3] + atomicAdd(&cur[b3], 1);
    pairs[p3] = ((unsigned)(d.w & (BKT_NODES-1)) << 17) | (unsigned)s.w;
  }
  for (int i = beg + (m4 << 2) + tid; i < end; i += 256){
    int d = dst[i], s = src[i];
    int b = d >> BKT_SHIFT;
    int p = base[b] + atomicAdd(&cur[b], 1);
    pairs[p] = ((unsigned)(d & (BKT_NODES-1)) << 17) | (unsigned)s;
  }
}

// one block (256 thr) per bucket: LDS hist -> scan -> offs2 (int2{beg,end}) + padded col
// reads the 4 shard sub-ranges of the bucket's FCAP region.
__global__ __launch_bounds__(256) void k_p2(const unsigned* __restrict__ pairs,
                                            const int* __restrict__ bktCur,
                                            int N, int2* __restrict__ offs2, int* __restrict__ col){
  __shared__ int sc[BKT_NODES], cu[BKT_NODES];
  int b = blockIdx.x, tid = threadIdx.x;
  int nbase = b << BKT_SHIFT;
  int bs = b * BKT_FCAP;
  sc[tid] = 0;
  __syncthreads();
  #pragma unroll
  for (int s = 0; s < 4; ++s){
    int ss_ = bs + s * BKT_SHARD;
    int se_ = ss_ + bktCur[b * 4 + s];
    for (int i = ss_ + tid; i < se_; i += 256)
      atomicAdd(&sc[pairs[i] >> 17], 1);
  }
  __syncthreads();
  int v = sc[tid];
  for (int o = 1; o < 256; o <<= 1){
    int x = (tid >= o) ? sc[tid - o] : 0;
    __syncthreads();
    sc[tid] += x;
    __syncthreads();
  }
  int ex = sc[tid] - v;
  cu[tid] = bs + ex;
  if (nbase + tid < N) offs2[nbase + tid] = make_int2(bs + ex, bs + ex + v);
  __syncthreads();
  #pragma unroll
  for (int s = 0; s < 4; ++s){
    int ss_ = bs + s * BKT_SHARD;
    int se_ = ss_ + bktCur[b * 4 + s];
    for (int i = ss_ + tid; i < se_; i += 256){
      unsigned pr = pairs[i];
      int p = atomicAdd(&cu[pr >> 17], 1);
      col[p] = (int)(pr & 0x1FFFFu);
    }
  }
}

// ---------------- MFMA GEMM 1: H(fp16)[n,64] = X(fp32)[n,128] @ W1, + logits ----------------
__global__ __launch_bounds__(256) void k_mgemm1(
    const float* __restrict__ X, const uint4* __restrict__ Wf,
    const float* __restrict__ a_src, const float* __restrict__ a_dst,
    uint2* __restrict__ H, float* __restrict__ as_, float* __restrict__ ad_, int n)
{
  int lane = threadIdx.x & 63, wv = threadIdx.x >> 6;
  int quad = lane >> 4, nn = lane & 15;
  int rowb = blockIdx.x * 64 + wv * 16;
  int row = rowb + nn;
  bool ok = row < n;
  int rowc = ok ? row : n - 1;

  f16x8 af[4][4];
  #pragma unroll
  for (int t = 0; t < 4; ++t)
    #pragma unroll
    for (int s = 0; s < 4; ++s){
      FU fu; fu.u = Wf[(t * 4 + s) * 64 + lane];
      af[t][s] = fu.f;
    }

  const float4* Xr = (const float4*)(X + (size_t)rowc * 128);
  float4 xb[4][2];
  #pragma unroll
  for (int s = 0; s < 4; ++s){
    xb[s][0] = Xr[s * 8 + quad * 2];
    xb[s][1] = Xr[s * 8 + quad * 2 + 1];
  }

  f32x4 acc[4] = {};
  #pragma unroll
  for (int s = 0; s < 4; ++s){
    f16x8 bf;
    bf[0] = (_Float16)xb[s][0].x; bf[1] = (_Float16)xb[s][0].y;
    bf[2] = (_Float16)xb[s][0].z; bf[3] = (_Float16)xb[s][0].w;
    bf[4] = (_Float16)xb[s][1].x; bf[5] = (_Float16)xb[s][1].y;
    bf[6] = (_Float16)xb[s][1].z; bf[7] = (_Float16)xb[s][1].w;
    #pragma unroll
    for (int t = 0; t < 4; ++t)
      acc[t] = __builtin_amdgcn_mfma_f32_16x16x32_f16(af[t][s], bf, acc[t], 0, 0, 0);
  }

  if (ok){
    #pragma unroll
    for (int t = 0; t < 4; ++t){
      H2U p0, p1;
      p0.h = __floats2half2_rn(acc[t][0], acc[t][1]);
      p1.h = __floats2half2_rn(acc[t][2], acc[t][3]);
      H[(size_t)row * 16 + t * 4 + quad] = make_uint2(p0.u, p1.u);
    }
  }
  float sl = 0.f, dl = 0.f;
  #pragma unroll
  for (int t = 0; t < 4; ++t){
    float4 a4 = ((const float4*)a_src)[t * 4 + quad];
    float4 d4 = ((const float4*)a_dst)[t * 4 + quad];
    sl += acc[t][0] * a4.x + acc[t][1] * a4.y + acc[t][2] * a4.z + acc[t][3] * a4.w;
    dl += acc[t][0] * d4.x + acc[t][1] * d4.y + acc[t][2] * d4.z + acc[t][3] * d4.w;
  }
  sl += __shfl_xor(sl, 16, 64); sl += __shfl_xor(sl, 32, 64);
  dl += __shfl_xor(dl, 16, 64); dl += __shfl_xor(dl, 32, 64);
  if (lane < 16 && ok){ as_[row] = sl; ad_[row] = dl; }
}

// ---------------- attention aggregation core (round-0 proven: 8 nodes/wave, x4 unroll) --
#define FMA8(e, hv) { const __half2* hp = (const __half2*)&(hv);               \
  a[0]=fmaf(e, __half2float(hp[0].x), a[0]); a[1]=fmaf(e, __half2float(hp[0].y), a[1]); \
  a[2]=fmaf(e, __half2float(hp[1].x), a[2]); a[3]=fmaf(e, __half2float(hp[1].y), a[3]); \
  a[4]=fmaf(e, __half2float(hp[2].x), a[4]); a[5]=fmaf(e, __half2float(hp[2].y), a[5]); \
  a[6]=fmaf(e, __half2float(hp[3].x), a[6]); a[7]=fmaf(e, __half2float(hp[3].y), a[7]); }

__device__ __forceinline__ void agg_core(
    const int2* __restrict__ offs2, const int* __restrict__ col,
    const uint4* __restrict__ H4, const float* __restrict__ as_, const float* __restrict__ ad_,
    int node, int c8, float& denom, float a[8])
{
  int2 be2 = offs2[node];
  int beg = be2.x, d = be2.y - be2.x;
  int maxd = d;
  maxd = max(maxd, __shfl_xor(maxd, 8, 64));
  maxd = max(maxd, __shfl_xor(maxd, 16, 64));
  maxd = max(maxd, __shfl_xor(maxd, 32, 64));
  float adv = ad_[node];
  float exs = __expf(lrelu(as_[node] + adv));
  uint4 hself = H4[(size_t)node * 8 + c8];
  denom = exs;
  { const __half2* hp = (const __half2*)&hself;
    #pragma unroll
    for (int i = 0; i < 4; ++i){
      a[2*i]   = exs * __half2float(hp[i].x);
      a[2*i+1] = exs * __half2float(hp[i].y);
    } }
  for (int j = 0; j < maxd; j += 4){
    int ss[4]; float asv[4]; uint4 hv[4];
    #pragma unroll
    for (int u = 0; u < 4; ++u) ss[u] = (j + u < d) ? col[beg + j + u] : 0;
    #pragma unroll
    for (int u = 0; u < 4; ++u) asv[u] = as_[ss[u]];
    #pragma unroll
    for (int u = 0; u < 4; ++u) hv[u] = H4[(size_t)ss[u] * 8 + c8];
    #pragma unroll
    for (int u = 0; u < 4; ++u){
      float e = (j + u < d) ? __expf(lrelu(asv[u] + adv)) : 0.f;
      denom += e;
      FMA8(e, hv[u])
    }
  }
}

// ---------------- fused agg1 + GEMM2: one block = 32 nodes ----------------
// Phase 1 (per wave, 8 nodes): layer-1 aggregation + ELU -> h1e rows into LDS (no HBM trip).
// Phase 2 (waves 0-1): h2 = h1e @ W2 via MFMA from LDS + layer-2 logits.
// Legal because mgemm2 is row-local: block consumes exactly the rows it produced.
__global__ __launch_bounds__(256) void k_agg1f(
    const int2* __restrict__ offs2, const int* __restrict__ col,
    const uint4* __restrict__ H4, const float* __restrict__ as_, const float* __restrict__ ad_,
    const float* __restrict__ bias, const uint4* __restrict__ W2f,
    const float* __restrict__ a_src2, const float* __restrict__ a_dst2,
    uint2* __restrict__ H2out, float* __restrict__ as2_, float* __restrict__ ad2_, int n)
{
  // 72 halves/row (36 uints, 144 B stride): breaks the 128 B power-of-2 bank pattern
  __shared__ unsigned uhl[32][36];
  int lane = threadIdx.x & 63, w = threadIdx.x >> 6;
  int m = lane >> 3, c8 = lane & 7;
  int node0 = blockIdx.x * 32 + w * 8 + m;
  bool ok = node0 < n;
  int node = ok ? node0 : n - 1;
  float denom; float a[8];
  agg_core(offs2, col, H4, as_, ad_, node, c8, denom, a);
  float inv = 1.f / denom;
  float4 b0 = *(const float4*)&bias[8 * c8];
  float4 b1 = *(const float4*)&bias[8 * c8 + 4];
  float bb[8] = {b0.x, b0.y, b0.z, b0.w, b1.x, b1.y, b1.z, b1.w};
  int ln = w * 8 + m;
  #pragma unroll
  for (int i = 0; i < 4; ++i){
    float v0 = elu_fast(fmaf(a[2*i],   inv, bb[2*i]));
    float v1 = elu_fast(fmaf(a[2*i+1], inv, bb[2*i+1]));
    __half2 h = __floats2half2_rn(v0, v1);
    uhl[ln][c8 * 4 + i] = *(unsigned*)&h;
  }
  __syncthreads();

  // -------- phase 2: 32-row GEMM on waves 0-1 (rows w*16+nn) --------
  if (w < 2){
    int quad = lane >> 4, nn = lane & 15;
    int lrow = w * 16 + nn;
    int row = blockIdx.x * 32 + lrow;
    bool ok2 = row < n;

    f16x8 af[4][2];
    #pragma unroll
    for (int t = 0; t < 4; ++t)
      #pragma unroll
      for (int s = 0; s < 2; ++s){
        FU fu; fu.u = W2f[(t * 2 + s) * 64 + lane];
        af[t][s] = fu.f;
      }

    f16x8 bf[2];
    #pragma unroll
    for (int s = 0; s < 2; ++s){
      FU fu; fu.u = ((const uint4*)&uhl[lrow][0])[s * 4 + quad];
      bf[s] = fu.f;
    }

    f32x4 acc[4] = {};
    #pragma unroll
    for (int s = 0; s < 2; ++s)
      #pragma unroll
      for (int t = 0; t < 4; ++t)
        acc[t] = __builtin_amdgcn_mfma_f32_16x16x32_f16(af[t][s], bf[s], acc[t], 0, 0, 0);

    if (ok2){
      #pragma unroll
      for (int t = 0; t < 4; ++t){
        H2U p0, p1;
        p0.h = __floats2half2_rn(acc[t][0], acc[t][1]);
        p1.h = __floats2half2_rn(acc[t][2], acc[t][3]);
        H2out[(size_t)row * 16 + t * 4 + quad] = make_uint2(p0.u, p1.u);
      }
    }
    float sl = 0.f, dl = 0.f;
    #pragma unroll
    for (int t = 0; t < 4; ++t){
      float4 a4 = ((const float4*)a_src2)[t * 4 + quad];
      float4 d4 = ((const float4*)a_dst2)[t * 4 + quad];
      sl += acc[t][0] * a4.x + acc[t][1] * a4.y + acc[t][2] * a4.z + acc[t][3] * a4.w;
      dl += acc[t][0] * d4.x + acc[t][1] * d4.y + acc[t][2] * d4.z + acc[t][3] * d4.w;
    }
    sl += __shfl_xor(sl, 16, 64); sl += __shfl_xor(sl, 32, 64);
    dl += __shfl_xor(dl, 16, 64); dl += __shfl_xor(dl, 32, 64);
    if (lane < 16 && ok2){ as2_[row] = sl; ad2_[row] = dl; }
  }
}

// ---------------- agg2: layer-2 aggregation + output head (round-0 proven) ----------------
__global__ __launch_bounds__(256) void k_agg2(
    const int2* __restrict__ offs2, const int* __restrict__ col,
    const uint4* __restrict__ H4, const float* __restrict__ as_, const float* __restrict__ ad_,
    const float* __restrict__ bias, const float* __restrict__ Wout, const float* __restrict__ bout,
    float* __restrict__ out, int n)
{
  int lane = threadIdx.x & 63, w = threadIdx.x >> 6;
  int m = lane >> 3, c8 = lane & 7;
  int node0 = blockIdx.x * 32 + w * 8 + m;
  bool ok = node0 < n;
  int node = ok ? node0 : n - 1;
  float denom; float a[8];
  agg_core(offs2, col, H4, as_, ad_, node, c8, denom, a);
  float inv = 1.f / denom;
  float4 b0 = *(const float4*)&bias[8 * c8];
  float4 b1 = *(const float4*)&bias[8 * c8 + 4];
  float4 w0 = *(const float4*)&Wout[8 * c8];
  float4 w1 = *(const float4*)&Wout[8 * c8 + 4];
  float bb[8] = {b0.x, b0.y, b0.z, b0.w, b1.x, b1.y, b1.z, b1.w};
  float ww[8] = {w0.x, w0.y, w0.z, w0.w, w1.x, w1.y, w1.z, w1.w};
  float p = 0.f;
  #pragma unroll
  for (int i = 0; i < 8; ++i)
    p += elu_fast(fmaf(a[i], inv, bb[i])) * ww[i];
  p += __shfl_xor(p, 1, 64); p += __shfl_xor(p, 2, 64); p += __shfl_xor(p, 4, 64);
  if (c8 == 0 && ok) out[node] = p + bout[0];
}

// ---------------- launch ----------------
extern "C" void kernel_launch(void* const* d_in, const int* in_sizes, int n_in,
                              void* d_out, int out_size, void* d_ws, size_t ws_size,
                              hipStream_t stream)
{
  const float* x    = (const float*)d_in[0];
  const int*   ei   = (const int*)d_in[1];   // int32 [2, E] flat
  const float* W1   = (const float*)d_in[2];
  const float* as1w = (const float*)d_in[3];
  const float* ad1w = (const float*)d_in[4];
  const float* b1   = (const float*)d_in[5];
  const float* W2   = (const float*)d_in[6];
  const float* as2w = (const float*)d_in[7];
  const float* ad2w = (const float*)d_in[8];
  const float* b2   = (const float*)d_in[9];
  const float* Wout = (const float*)d_in[10];
  const float* bout = (const float*)d_in[11];
  float* out = (float*)d_out;

  const int N = in_sizes[0] / 128;
  const int E = in_sizes[1] / 2;
  const int* srcA = ei;
  const int* dstA = ei + E;
  const int B = (N + BKT_NODES - 1) >> BKT_SHIFT;   // 391 (<= BKT_CAP); src < 2^17 required

  char* p = (char*)d_ws;
  auto alloc = [&](size_t bytes){ char* r = p; p += (bytes + 255) & ~255ull; return r; };
  int*   bktCur = (int*)alloc(BKT_CAP * 4 * 4);              // x4 shards
  int2*  offs2  = (int2*)alloc((size_t)N * 8);
  int*   col    = (int*)alloc((size_t)B * BKT_FCAP * 4);     // padded CSR col (9.6 MB)
  float* vas1 = (float*)alloc((size_t)N * 4);
  float* vad1 = (float*)alloc((size_t)N * 4);
  float* vas2 = (float*)alloc((size_t)N * 4);
  float* vad2 = (float*)alloc((size_t)N * 4);
  uint4* w1f  = (uint4*)alloc(16 * 64 * 16);
  uint4* w2f  = (uint4*)alloc(8 * 64 * 16);
  uint2* h1   = (uint2*)alloc((size_t)N * 64 * 2);   // fp16 [N,64] (layer-1 features)
  uint2* h2   = (uint2*)alloc((size_t)N * 64 * 2);   // fp16 [N,64] (layer-2 features)
  unsigned* pairs = (unsigned*)h1;  // padded pairs (9.6 MB) dead before k_mgemm1 writes h1 (12.8 MB)

  hipMemsetAsync(bktCur, 0, BKT_CAP * 4 * 4, stream);

  int nchunk = (E + P1_CHUNK - 1) / P1_CHUNK;
  k_p1<<<nchunk, 256, 0, stream>>>(srcA, dstA, E, B, bktCur, pairs, W1, W2, w1f, w2f);
  k_p2<<<B, 256, 0, stream>>>(pairs, bktCur, N, offs2, col);

  int gblocks = (N + 63) / 64;
  int ablocks = (N + 31) / 32;
  k_mgemm1<<<gblocks, 256, 0, stream>>>(x, w1f, as1w, ad1w, h1, vas1, vad1, N);
  k_agg1f <<<ablocks, 256, 0, stream>>>(offs2, col, (const uint4*)h1, vas1, vad1, b1,
                                        w2f, as2w, ad2w, h2, vas2, vad2, N);
  k_agg2  <<<ablocks, 256, 0, stream>>>(offs2, col, (const uint4*)h2, vas2, vad2, b2, Wout, bout, out, N);
}

// Round 6
// 234.824 us; speedup vs baseline: 1.1002x; 1.0446x over previous
//
#include <hip/hip_runtime.h>
#include <hip/hip_fp16.h>
#include <math.h>

#define NEG_SLOPE 0.2f
#define BKT_SHIFT 8
#define BKT_NODES (1 << BKT_SHIFT)       // 256 nodes per bucket
#define BKT_CAP 512                      // >= B = ceil(N/256) = 391
#define BKT_FCAP 6144                    // fixed edge capacity per bucket (avg 4092)
#define BKT_SHARD (BKT_FCAP / 4)         // 1536 per shard (expected ~1026, 16-sigma margin)
#define P1_CHUNK 4096

typedef _Float16 f16x8 __attribute__((ext_vector_type(8)));
typedef float    f32x4 __attribute__((ext_vector_type(4)));
union FU  { uint4 u; f16x8 f; };
union H2U { __half2 h; unsigned u; };

__device__ __forceinline__ float lrelu(float x){ return fmaxf(x, NEG_SLOPE * x); }
__device__ __forceinline__ float elu_fast(float x){
  float t = __expf(fminf(x, 0.f)) - 1.f;
  return x > 0.f ? x : t;
}

// ---------------- bucketed CSR build (single-pass, fixed-cap buckets) ----------------
// bucket b = dst >> 8. pairs packed: (dst&255)<<17 | src  (src < 2^17)
// bktCur sharded x4 by blockIdx&3 to cut same-address atomic serialization.
// Block 0 additionally packs the W fragments (saves a dispatch).

__global__ __launch_bounds__(256) void k_p1(const int* __restrict__ src, const int* __restrict__ dst,
                                            int E, int B, int* __restrict__ bktCur,
                                            unsigned* __restrict__ pairs,
                                            const float* __restrict__ W1, const float* __restrict__ W2,
                                            uint4* __restrict__ W1f, uint4* __restrict__ W2f){
  __shared__ int h[BKT_CAP], base[BKT_CAP], cur[BKT_CAP];
  int tid = threadIdx.x;
  if (blockIdx.x == 0){
    // W1 fragments: fs = t*4+s (t,s in 0..3); W2: fs = t*2+s (t 0..3, s 0..1)
    for (int idx = tid; idx < 16 * 64; idx += 256){
      int lane = idx & 63, fs = idx >> 6;
      int t = fs >> 2, s = fs & 3;
      int m = lane & 15, quad = lane >> 4;
      f16x8 v;
      #pragma unroll
      for (int j = 0; j < 8; ++j)
        v[j] = (_Float16)W1[(s * 32 + quad * 8 + j) * 64 + t * 16 + m];
      FU fu; fu.f = v;
      W1f[fs * 64 + lane] = fu.u;
    }
    for (int idx = tid; idx < 8 * 64; idx += 256){
      int lane = idx & 63, fs = idx >> 6;
      int t = fs >> 1, s = fs & 1;
      int m = lane & 15, quad = lane >> 4;
      f16x8 v;
      #pragma unroll
      for (int j = 0; j < 8; ++j)
        v[j] = (_Float16)W2[(s * 32 + quad * 8 + j) * 64 + t * 16 + m];
      FU fu; fu.f = v;
      W2f[fs * 64 + lane] = fu.u;
    }
  }
  for (int i = tid; i < BKT_CAP; i += 256){ h[i] = 0; cur[i] = 0; }
  __syncthreads();
  int beg = blockIdx.x * P1_CHUNK;
  int end = min(beg + P1_CHUNK, E);
  int shard = blockIdx.x & 3;
  int m4 = (end - beg) >> 2;
  const int4* d4 = (const int4*)(dst + beg);
  const int4* s4 = (const int4*)(src + beg);
  for (int i = tid; i < m4; i += 256){
    int4 d = d4[i];
    atomicAdd(&h[d.x >> BKT_SHIFT], 1); atomicAdd(&h[d.y >> BKT_SHIFT], 1);
    atomicAdd(&h[d.z >> BKT_SHIFT], 1); atomicAdd(&h[d.w >> BKT_SHIFT], 1);
  }
  for (int i = beg + (m4 << 2) + tid; i < end; i += 256)
    atomicAdd(&h[dst[i] >> BKT_SHIFT], 1);
  __syncthreads();
  for (int i = tid; i < B; i += 256)
    if (h[i]) base[i] = i * BKT_FCAP + shard * BKT_SHARD + atomicAdd(&bktCur[i * 4 + shard], h[i]);
  __syncthreads();
  for (int i = tid; i < m4; i += 256){
    int4 d = d4[i]; int4 s = s4[i];
    int b0 = d.x >> BKT_SHIFT, b1 = d.y >> BKT_SHIFT, b2 = d.z >> BKT_SHIFT, b3 = d.w >> BKT_SHIFT;
    int p0 = base[b0] + atomicAdd(&cur[b0], 1);
    pairs[p0] = ((unsigned)(d.x & (BKT_NODES-1)) << 17) | (unsigned)s.x;
    int p1 = base[b1] + atomicAdd(&cur[b1], 1);
    pairs[p1] = ((unsigned)(d.y & (BKT_NODES-1)) << 17) | (unsigned)s.y;
    int p2 = base[b2] + atomicAdd(&cur[b2], 1);
    pairs[p2] = ((unsigned)(d.z & (BKT_NODES-1)) << 17) | (unsigned)s.z;
    int p3 = base[b3] + atomicAdd(&cur[b3], 1);
    pairs[p3] = ((unsigned)(d.w & (BKT_NODES-1)) << 17) | (unsigned)s.w;
  }
  for (int i = beg + (m4 << 2) + tid; i < end; i += 256){
    int d = dst[i], s = src[i];
    int b = d >> BKT_SHIFT;
    int p = base[b] + atomicAdd(&cur[b], 1);
    pairs[p] = ((unsigned)(d & (BKT_NODES-1)) << 17) | (unsigned)s;
  }
}

// one block (256 thr) per bucket: LDS hist -> scan -> offs2 (int2{beg,end}) + padded col
// reads the 4 shard sub-ranges of the bucket's FCAP region.
__device__ __forceinline__ void p2_body(const unsigned* __restrict__ pairs,
                                        const int* __restrict__ bktCur,
                                        int N, int2* __restrict__ offs2, int* __restrict__ col, int b){
  __shared__ int sc[BKT_NODES], cu[BKT_NODES];
  int tid = threadIdx.x;
  int nbase = b << BKT_SHIFT;
  int bs = b * BKT_FCAP;
  sc[tid] = 0;
  __syncthreads();
  #pragma unroll
  for (int s = 0; s < 4; ++s){
    int ss_ = bs + s * BKT_SHARD;
    int se_ = ss_ + bktCur[b * 4 + s];
    for (int i = ss_ + tid; i < se_; i += 256)
      atomicAdd(&sc[pairs[i] >> 17], 1);
  }
  __syncthreads();
  int v = sc[tid];
  for (int o = 1; o < 256; o <<= 1){
    int x = (tid >= o) ? sc[tid - o] : 0;
    __syncthreads();
    sc[tid] += x;
    __syncthreads();
  }
  int ex = sc[tid] - v;
  cu[tid] = bs + ex;
  if (nbase + tid < N) offs2[nbase + tid] = make_int2(bs + ex, bs + ex + v);
  __syncthreads();
  #pragma unroll
  for (int s = 0; s < 4; ++s){
    int ss_ = bs + s * BKT_SHARD;
    int se_ = ss_ + bktCur[b * 4 + s];
    for (int i = ss_ + tid; i < se_; i += 256){
      unsigned pr = pairs[i];
      int p = atomicAdd(&cu[pr >> 17], 1);
      col[p] = (int)(pr & 0x1FFFFu);
    }
  }
}

// ---------------- MFMA GEMM 1 body: H(fp16)[n,64] = X(fp32)[n,128] @ W1, + logits --------
__device__ __forceinline__ void mg1_body(
    const float* __restrict__ X, const uint4* __restrict__ Wf,
    const float* __restrict__ a_src, const float* __restrict__ a_dst,
    uint2* __restrict__ H, float* __restrict__ as_, float* __restrict__ ad_, int n, int bb)
{
  int lane = threadIdx.x & 63, wv = threadIdx.x >> 6;
  int quad = lane >> 4, nn = lane & 15;
  int rowb = bb * 64 + wv * 16;
  int row = rowb + nn;
  bool ok = row < n;
  int rowc = ok ? row : n - 1;

  f16x8 af[4][4];
  #pragma unroll
  for (int t = 0; t < 4; ++t)
    #pragma unroll
    for (int s = 0; s < 4; ++s){
      FU fu; fu.u = Wf[(t * 4 + s) * 64 + lane];
      af[t][s] = fu.f;
    }

  const float4* Xr = (const float4*)(X + (size_t)rowc * 128);
  float4 xb[4][2];
  #pragma unroll
  for (int s = 0; s < 4; ++s){
    xb[s][0] = Xr[s * 8 + quad * 2];
    xb[s][1] = Xr[s * 8 + quad * 2 + 1];
  }

  f32x4 acc[4] = {};
  #pragma unroll
  for (int s = 0; s < 4; ++s){
    f16x8 bf;
    bf[0] = (_Float16)xb[s][0].x; bf[1] = (_Float16)xb[s][0].y;
    bf[2] = (_Float16)xb[s][0].z; bf[3] = (_Float16)xb[s][0].w;
    bf[4] = (_Float16)xb[s][1].x; bf[5] = (_Float16)xb[s][1].y;
    bf[6] = (_Float16)xb[s][1].z; bf[7] = (_Float16)xb[s][1].w;
    #pragma unroll
    for (int t = 0; t < 4; ++t)
      acc[t] = __builtin_amdgcn_mfma_f32_16x16x32_f16(af[t][s], bf, acc[t], 0, 0, 0);
  }

  if (ok){
    #pragma unroll
    for (int t = 0; t < 4; ++t){
      H2U p0, p1;
      p0.h = __floats2half2_rn(acc[t][0], acc[t][1]);
      p1.h = __floats2half2_rn(acc[t][2], acc[t][3]);
      H[(size_t)row * 16 + t * 4 + quad] = make_uint2(p0.u, p1.u);
    }
  }
  float sl = 0.f, dl = 0.f;
  #pragma unroll
  for (int t = 0; t < 4; ++t){
    float4 a4 = ((const float4*)a_src)[t * 4 + quad];
    float4 d4 = ((const float4*)a_dst)[t * 4 + quad];
    sl += acc[t][0] * a4.x + acc[t][1] * a4.y + acc[t][2] * a4.z + acc[t][3] * a4.w;
    dl += acc[t][0] * d4.x + acc[t][1] * d4.y + acc[t][2] * d4.z + acc[t][3] * d4.w;
  }
  sl += __shfl_xor(sl, 16, 64); sl += __shfl_xor(sl, 32, 64);
  dl += __shfl_xor(dl, 16, 64); dl += __shfl_xor(dl, 32, 64);
  if (lane < 16 && ok){ as_[row] = sl; ad_[row] = dl; }
}

// fused: blocks [0, p2B) run CSR finalize, blocks [p2B, ...) run GEMM1.
// Independent: p2 reads pairs (aliased to h2), mgemm1 writes h1 — disjoint.
// Complementary pipes: p2 = LDS-atomic/latency, mgemm1 = HBM-stream/MFMA.
__global__ __launch_bounds__(256) void k_fused(
    const unsigned* __restrict__ pairs, const int* __restrict__ bktCur,
    int N, int2* __restrict__ offs2, int* __restrict__ col, int p2B,
    const float* __restrict__ X, const uint4* __restrict__ Wf,
    const float* __restrict__ a_src, const float* __restrict__ a_dst,
    uint2* __restrict__ H, float* __restrict__ as_, float* __restrict__ ad_)
{
  if ((int)blockIdx.x < p2B)
    p2_body(pairs, bktCur, N, offs2, col, blockIdx.x);
  else
    mg1_body(X, Wf, a_src, a_dst, H, as_, ad_, N, blockIdx.x - p2B);
}

// ---------------- attention aggregation core (round-0 proven: 8 nodes/wave, x4 unroll) --
#define FMA8(e, hv) { const __half2* hp = (const __half2*)&(hv);               \
  a[0]=fmaf(e, __half2float(hp[0].x), a[0]); a[1]=fmaf(e, __half2float(hp[0].y), a[1]); \
  a[2]=fmaf(e, __half2float(hp[1].x), a[2]); a[3]=fmaf(e, __half2float(hp[1].y), a[3]); \
  a[4]=fmaf(e, __half2float(hp[2].x), a[4]); a[5]=fmaf(e, __half2float(hp[2].y), a[5]); \
  a[6]=fmaf(e, __half2float(hp[3].x), a[6]); a[7]=fmaf(e, __half2float(hp[3].y), a[7]); }

__device__ __forceinline__ void agg_core(
    const int2* __restrict__ offs2, const int* __restrict__ col,
    const uint4* __restrict__ H4, const float* __restrict__ as_, const float* __restrict__ ad_,
    int node, int c8, float& denom, float a[8])
{
  int2 be2 = offs2[node];
  int beg = be2.x, d = be2.y - be2.x;
  int maxd = d;
  maxd = max(maxd, __shfl_xor(maxd, 8, 64));
  maxd = max(maxd, __shfl_xor(maxd, 16, 64));
  maxd = max(maxd, __shfl_xor(maxd, 32, 64));
  float adv = ad_[node];
  float exs = __expf(lrelu(as_[node] + adv));
  uint4 hself = H4[(size_t)node * 8 + c8];
  denom = exs;
  { const __half2* hp = (const __half2*)&hself;
    #pragma unroll
    for (int i = 0; i < 4; ++i){
      a[2*i]   = exs * __half2float(hp[i].x);
      a[2*i+1] = exs * __half2float(hp[i].y);
    } }
  for (int j = 0; j < maxd; j += 4){
    int ss[4]; float asv[4]; uint4 hv[4];
    #pragma unroll
    for (int u = 0; u < 4; ++u) ss[u] = (j + u < d) ? col[beg + j + u] : 0;
    #pragma unroll
    for (int u = 0; u < 4; ++u) asv[u] = as_[ss[u]];
    #pragma unroll
    for (int u = 0; u < 4; ++u) hv[u] = H4[(size_t)ss[u] * 8 + c8];
    #pragma unroll
    for (int u = 0; u < 4; ++u){
      float e = (j + u < d) ? __expf(lrelu(asv[u] + adv)) : 0.f;
      denom += e;
      FMA8(e, hv[u])
    }
  }
}

// ---------------- fused agg1 + GEMM2: one block = 32 nodes ----------------
// Phase 1 (per wave, 8 nodes): layer-1 aggregation + ELU -> h1e rows into LDS (no HBM trip).
// Phase 2 (waves 0-1): h2 = h1e @ W2 via MFMA from LDS + layer-2 logits.
__global__ __launch_bounds__(256) void k_agg1f(
    const int2* __restrict__ offs2, const int* __restrict__ col,
    const uint4* __restrict__ H4, const float* __restrict__ as_, const float* __restrict__ ad_,
    const float* __restrict__ bias, const uint4* __restrict__ W2f,
    const float* __restrict__ a_src2, const float* __restrict__ a_dst2,
    uint2* __restrict__ H2out, float* __restrict__ as2_, float* __restrict__ ad2_, int n)
{
  // 72 halves/row (36 uints, 144 B stride): breaks the 128 B power-of-2 bank pattern
  __shared__ unsigned uhl[32][36];
  int lane = threadIdx.x & 63, w = threadIdx.x >> 6;
  int m = lane >> 3, c8 = lane & 7;
  int node0 = blockIdx.x * 32 + w * 8 + m;
  bool ok = node0 < n;
  int node = ok ? node0 : n - 1;
  float denom; float a[8];
  agg_core(offs2, col, H4, as_, ad_, node, c8, denom, a);
  float inv = 1.f / denom;
  float4 b0 = *(const float4*)&bias[8 * c8];
  float4 b1 = *(const float4*)&bias[8 * c8 + 4];
  float bb[8] = {b0.x, b0.y, b0.z, b0.w, b1.x, b1.y, b1.z, b1.w};
  int ln = w * 8 + m;
  #pragma unroll
  for (int i = 0; i < 4; ++i){
    float v0 = elu_fast(fmaf(a[2*i],   inv, bb[2*i]));
    float v1 = elu_fast(fmaf(a[2*i+1], inv, bb[2*i+1]));
    __half2 h = __floats2half2_rn(v0, v1);
    uhl[ln][c8 * 4 + i] = *(unsigned*)&h;
  }
  __syncthreads();

  // -------- phase 2: 32-row GEMM on waves 0-1 (rows w*16+nn) --------
  if (w < 2){
    int quad = lane >> 4, nn = lane & 15;
    int lrow = w * 16 + nn;
    int row = blockIdx.x * 32 + lrow;
    bool ok2 = row < n;

    f16x8 af[4][2];
    #pragma unroll
    for (int t = 0; t < 4; ++t)
      #pragma unroll
      for (int s = 0; s < 2; ++s){
        FU fu; fu.u = W2f[(t * 2 + s) * 64 + lane];
        af[t][s] = fu.f;
      }

    f16x8 bf[2];
    #pragma unroll
    for (int s = 0; s < 2; ++s){
      FU fu; fu.u = ((const uint4*)&uhl[lrow][0])[s * 4 + quad];
      bf[s] = fu.f;
    }

    f32x4 acc[4] = {};
    #pragma unroll
    for (int s = 0; s < 2; ++s)
      #pragma unroll
      for (int t = 0; t < 4; ++t)
        acc[t] = __builtin_amdgcn_mfma_f32_16x16x32_f16(af[t][s], bf[s], acc[t], 0, 0, 0);

    if (ok2){
      #pragma unroll
      for (int t = 0; t < 4; ++t){
        H2U p0, p1;
        p0.h = __floats2half2_rn(acc[t][0], acc[t][1]);
        p1.h = __floats2half2_rn(acc[t][2], acc[t][3]);
        H2out[(size_t)row * 16 + t * 4 + quad] = make_uint2(p0.u, p1.u);
      }
    }
    float sl = 0.f, dl = 0.f;
    #pragma unroll
    for (int t = 0; t < 4; ++t){
      float4 a4 = ((const float4*)a_src2)[t * 4 + quad];
      float4 d4 = ((const float4*)a_dst2)[t * 4 + quad];
      sl += acc[t][0] * a4.x + acc[t][1] * a4.y + acc[t][2] * a4.z + acc[t][3] * a4.w;
      dl += acc[t][0] * d4.x + acc[t][1] * d4.y + acc[t][2] * d4.z + acc[t][3] * d4.w;
    }
    sl += __shfl_xor(sl, 16, 64); sl += __shfl_xor(sl, 32, 64);
    dl += __shfl_xor(dl, 16, 64); dl += __shfl_xor(dl, 32, 64);
    if (lane < 16 && ok2){ as2_[row] = sl; ad2_[row] = dl; }
  }
}

// ---------------- agg2: layer-2 aggregation + output head (round-0 proven) ----------------
__global__ __launch_bounds__(256) void k_agg2(
    const int2* __restrict__ offs2, const int* __restrict__ col,
    const uint4* __restrict__ H4, const float* __restrict__ as_, const float* __restrict__ ad_,
    const float* __restrict__ bias, const float* __restrict__ Wout, const float* __restrict__ bout,
    float* __restrict__ out, int n)
{
  int lane = threadIdx.x & 63, w = threadIdx.x >> 6;
  int m = lane >> 3, c8 = lane & 7;
  int node0 = blockIdx.x * 32 + w * 8 + m;
  bool ok = node0 < n;
  int node = ok ? node0 : n - 1;
  float denom; float a[8];
  agg_core(offs2, col, H4, as_, ad_, node, c8, denom, a);
  float inv = 1.f / denom;
  float4 b0 = *(const float4*)&bias[8 * c8];
  float4 b1 = *(const float4*)&bias[8 * c8 + 4];
  float4 w0 = *(const float4*)&Wout[8 * c8];
  float4 w1 = *(const float4*)&Wout[8 * c8 + 4];
  float bb[8] = {b0.x, b0.y, b0.z, b0.w, b1.x, b1.y, b1.z, b1.w};
  float ww[8] = {w0.x, w0.y, w0.z, w0.w, w1.x, w1.y, w1.z, w1.w};
  float p = 0.f;
  #pragma unroll
  for (int i = 0; i < 8; ++i)
    p += elu_fast(fmaf(a[i], inv, bb[i])) * ww[i];
  p += __shfl_xor(p, 1, 64); p += __shfl_xor(p, 2, 64); p += __shfl_xor(p, 4, 64);
  if (c8 == 0 && ok) out[node] = p + bout[0];
}

// ---------------- launch ----------------
extern "C" void kernel_launch(void* const* d_in, const int* in_sizes, int n_in,
                              void* d_out, int out_size, void* d_ws, size_t ws_size,
                              hipStream_t stream)
{
  const float* x    = (const float*)d_in[0];
  const int*   ei   = (const int*)d_in[1];   // int32 [2, E] flat
  const float* W1   = (const float*)d_in[2];
  const float* as1w = (const float*)d_in[3];
  const float* ad1w = (const float*)d_in[4];
  const float* b1   = (const float*)d_in[5];
  const float* W2   = (const float*)d_in[6];
  const float* as2w = (const float*)d_in[7];
  const float* ad2w = (const float*)d_in[8];
  const float* b2   = (const float*)d_in[9];
  const float* Wout = (const float*)d_in[10];
  const float* bout = (const float*)d_in[11];
  float* out = (float*)d_out;

  const int N = in_sizes[0] / 128;
  const int E = in_sizes[1] / 2;
  const int* srcA = ei;
  const int* dstA = ei + E;
  const int B = (N + BKT_NODES - 1) >> BKT_SHIFT;   // 391 (<= BKT_CAP); src < 2^17 required

  char* p = (char*)d_ws;
  auto alloc = [&](size_t bytes){ char* r = p; p += (bytes + 255) & ~255ull; return r; };
  int*   bktCur = (int*)alloc(BKT_CAP * 4 * 4);              // x4 shards
  int2*  offs2  = (int2*)alloc((size_t)N * 8);
  int*   col    = (int*)alloc((size_t)B * BKT_FCAP * 4);     // padded CSR col (9.6 MB)
  float* vas1 = (float*)alloc((size_t)N * 4);
  float* vad1 = (float*)alloc((size_t)N * 4);
  float* vas2 = (float*)alloc((size_t)N * 4);
  float* vad2 = (float*)alloc((size_t)N * 4);
  uint4* w1f  = (uint4*)alloc(16 * 64 * 16);
  uint4* w2f  = (uint4*)alloc(8 * 64 * 16);
  uint2* h1   = (uint2*)alloc((size_t)N * 64 * 2);   // fp16 [N,64] (layer-1 features)
  uint2* h2   = (uint2*)alloc((size_t)N * 64 * 2);   // fp16 [N,64] (layer-2 features)
  // pairs aliases h2 (NOT h1): p2 reads pairs while mgemm1 writes h1 concurrently;
  // h2 is first written by k_agg1f, after pairs is dead.
  unsigned* pairs = (unsigned*)h2;

  hipMemsetAsync(bktCur, 0, BKT_CAP * 4 * 4, stream);

  int nchunk = (E + P1_CHUNK - 1) / P1_CHUNK;
  k_p1<<<nchunk, 256, 0, stream>>>(srcA, dstA, E, B, bktCur, pairs, W1, W2, w1f, w2f);

  int gblocks = (N + 63) / 64;
  int ablocks = (N + 31) / 32;
  // p2 (CSR finalize) || mgemm1 (layer-1 GEMM) — independent, complementary pipes
  k_fused<<<B + gblocks, 256, 0, stream>>>(pairs, bktCur, N, offs2, col, B,
                                           x, w1f, as1w, ad1w, h1, vas1, vad1);
  k_agg1f <<<ablocks, 256, 0, stream>>>(offs2, col, (const uint4*)h1, vas1, vad1, b1,
                                        w2f, as2w, ad2w, h2, vas2, vad2, N);
  k_agg2  <<<ablocks, 256, 0, stream>>>(offs2, col, (const uint4*)h2, vas2, vad2, b2, Wout, bout, out, N);
}